// Round 8
// baseline (74.364 us; speedup 1.0000x reference)
//
#include <hip/hip_runtime.h>
#include <math.h>

#define EPS 1e-6f
#define FLT_BIG 3.402823466e+38f

constexpr int BLK = 256;     // threads per block
constexpr int MPT = 4;       // m's per thread in phase 1
constexpr int NCHUNK = 32;   // l-chunks (grid.y)
constexpr int NMB = 4;       // m-blocks (grid.x), each covers BLK*MPT m's
constexpr int MAXCL = 256;   // LDS float4 capacity (4 KiB)

// Single fused kernel. Grid (NMB, NCHUNK, B), 256 threads.
// Phase 1: per (b,chunk) stage CL points of c1 as (||p||^2,-2x,-2y,-2z); each
//   thread computes chunk-partial min_l(||p||^2 - 2 p.q) + ||q||^2 for MPT m's
//   of its mblock and stores to part[b][chunk][m] (plain coalesced stores).
// Elect A: last of the 32 chunk-blocks per (b,mb) (atomic counter, init -1 by
//   the preceding 80-byte memset) reduces min-over-chunks for its 1024 m's,
//   sqrts, fixed-order block-sum -> psum[b][mb].
// Elect B: last of the 4 mb-tails per b writes out[b] = sum(psum)*res/L2.
// No spin-waits anywhere; all merges order-independent or fixed-order.
__global__ void __launch_bounds__(BLK)
k_all(const float* __restrict__ c1, const float* __restrict__ c2,
      const float* __restrict__ res, float* __restrict__ part,
      float* __restrict__ psum, int* __restrict__ cntA, int* __restrict__ cntB,
      float* __restrict__ out, int L1, int L2, int CL) {
    __shared__ float4 tile[MAXCL];
    __shared__ float red[BLK];
    __shared__ int flag;

    const int mb = blockIdx.x, chunk = blockIdx.y, b = blockIdx.z;
    const int tid = threadIdx.x;

    // ---------- phase 1 ----------
    const int l0 = chunk * CL;
    const int nl = min(CL, L1 - l0);

    const float* src = c1 + ((size_t)b * L1 + l0) * 3;
    for (int i = tid; i < nl; i += BLK) {
        float x = src[3 * i], y = src[3 * i + 1], z = src[3 * i + 2];
        tile[i] = make_float4(fmaf(x, x, fmaf(y, y, z * z)),
                              -2.0f * x, -2.0f * y, -2.0f * z);
    }
    __syncthreads();

    const int mbase = mb * (BLK * MPT) + tid;

    float q0[MPT], q1[MPT], q2[MPT], mn[MPT];
    #pragma unroll
    for (int j = 0; j < MPT; ++j) {
        const int m = mbase + j * BLK;
        if (m < L2) {
            const float* q = c2 + ((size_t)b * L2 + m) * 3;
            q0[j] = q[0] - EPS; q1[j] = q[1] - EPS; q2[j] = q[2] - EPS;
        } else {
            q0[j] = q1[j] = q2[j] = 0.0f;
        }
        mn[j] = FLT_BIG;
    }

    int l = 0;
    #pragma unroll 2
    for (; l + 2 <= nl; l += 2) {
        float4 pa = tile[l], pb = tile[l + 1];
        #pragma unroll
        for (int j = 0; j < MPT; ++j) {
            float ta = fmaf(pa.w, q2[j], fmaf(pa.z, q1[j], fmaf(pa.y, q0[j], pa.x)));
            float tb = fmaf(pb.w, q2[j], fmaf(pb.z, q1[j], fmaf(pb.y, q0[j], pb.x)));
            mn[j] = fminf(mn[j], fminf(ta, tb));
        }
    }
    for (; l < nl; ++l) {
        float4 p = tile[l];
        #pragma unroll
        for (int j = 0; j < MPT; ++j)
            mn[j] = fminf(mn[j], fmaf(p.w, q2[j], fmaf(p.z, q1[j], fmaf(p.y, q0[j], p.x))));
    }

    float* dst = part + ((size_t)b * NCHUNK + chunk) * L2;
    #pragma unroll
    for (int j = 0; j < MPT; ++j) {
        const int m = mbase + j * BLK;
        if (m < L2) {
            const float qq = fmaf(q0[j], q0[j], fmaf(q1[j], q1[j], q2[j] * q2[j]));
            dst[m] = mn[j] + qq;
        }
    }

    // ---------- elect A: last chunk-block of this (b, mb) ----------
    __threadfence();                       // release part stores (device scope)
    if (tid == 0) flag = atomicAdd(&cntA[b * NMB + mb], 1);
    __syncthreads();
    if (flag != NCHUNK - 2) return;        // counter init -1: last old == 30
    __threadfence();                       // acquire other blocks' part stores

    float sum = 0.0f;
    #pragma unroll
    for (int j = 0; j < MPT; ++j) {
        const int m = mbase + j * BLK;
        if (m < L2) {
            float v = FLT_BIG;
            #pragma unroll 8
            for (int c = 0; c < NCHUNK; ++c)
                v = fminf(v, part[((size_t)b * NCHUNK + c) * L2 + m]);
            sum += sqrtf(fmaxf(v, 0.0f));
        }
    }
    red[tid] = sum;
    __syncthreads();
    for (int s = BLK / 2; s > 0; s >>= 1) {
        if (tid < s) red[tid] += red[tid + s];
        __syncthreads();
    }

    // ---------- elect B: last mb-tail of this b ----------
    if (tid == 0) {
        psum[b * NMB + mb] = red[0];
        __threadfence();
        int old = atomicAdd(&cntB[b], 1);
        if (old == NMB - 2) {              // init -1: last old == 2
            __threadfence();
            float s = 0.0f;
            #pragma unroll
            for (int k = 0; k < NMB; ++k) s += psum[b * NMB + k];
            out[b] = s * res[0] / (float)L2;
        }
    }
}

extern "C" void kernel_launch(void* const* d_in, const int* in_sizes, int n_in,
                              void* d_out, int out_size, void* d_ws, size_t ws_size,
                              hipStream_t stream) {
    const float* c1  = (const float*)d_in[0];
    const float* c2  = (const float*)d_in[1];
    const float* res = (const float*)d_in[2];
    float* out = (float*)d_out;

    const int B = out_size;                 // 4
    const int D = 3;
    const int L1 = in_sizes[0] / (B * D);   // 4096
    const int L2 = in_sizes[1] / (B * D);   // 4096

    // ws layout: part[B][NCHUNK][L2] | psum[B][NMB] | cntA[B][NMB] | cntB[B]
    float* part = (float*)d_ws;
    float* psum = part + (size_t)B * NCHUNK * L2;
    int*   cntA = (int*)(psum + B * NMB);
    int*   cntB = cntA + B * NMB;

    // Init all counters to -1 (0xFF bytes). In-stream -> re-runs every replay.
    hipMemsetAsync(cntA, 0xFF, (size_t)(B * NMB + B) * sizeof(int), stream);

    const int CL = (L1 + NCHUNK - 1) / NCHUNK;   // 128
    dim3 grid(NMB, NCHUNK, B);
    k_all<<<grid, BLK, 0, stream>>>(c1, c2, res, part, psum, cntA, cntB,
                                    out, L1, L2, CL);
}

// Round 9
// 19.301 us; speedup vs baseline: 3.8529x; 3.8529x over previous
//
#include <hip/hip_runtime.h>
#include <math.h>

#define EPS 1e-6f
#define FLT_BIG 3.402823466e+38f

constexpr int BLK = 256;     // threads per block
constexpr int MPT = 8;       // m's per thread (amortize LDS broadcast over 8 m's)
constexpr int NCHUNK = 32;   // l-chunks (grid.y)
constexpr int NMB = 2;       // m-blocks (grid.x): NMB*BLK*MPT = 4096 = L2
constexpr int CLK = 128;     // l's per chunk (L1 / NCHUNK)

// Dispatch 1. Grid (NMB, NCHUNK, B), 256 threads.
// Per (b,chunk): stage CLK points of c1 as (||p||^2,-2x,-2y,-2z) in LDS; each
// thread computes chunk-partial min_l(||p||^2 - 2 p.q) + ||q||^2 for 8 m's
// (q = c2[m] - eps) and stores to part[b][chunk][m]. Plain stores, no atomics.
// Block (0,0,b) thread 0 also zeroes out[b] (safe: k_tail is stream-ordered
// after this kernel; re-runs every replay).
__global__ void __launch_bounds__(BLK)
k_min(const float* __restrict__ c1, const float* __restrict__ c2,
      float* __restrict__ part, float* __restrict__ out, int L1, int L2) {
    __shared__ float4 tile[CLK];

    const int mb = blockIdx.x, chunk = blockIdx.y, b = blockIdx.z;
    const int tid = threadIdx.x;

    if (mb == 0 && chunk == 0 && tid == 0) out[b] = 0.0f;

    const int l0 = chunk * CLK;
    const float* src = c1 + ((size_t)b * L1 + l0) * 3;
    if (tid < CLK) {
        float x = src[3 * tid], y = src[3 * tid + 1], z = src[3 * tid + 2];
        tile[tid] = make_float4(fmaf(x, x, fmaf(y, y, z * z)),
                                -2.0f * x, -2.0f * y, -2.0f * z);
    }
    __syncthreads();

    const int mbase = mb * (BLK * MPT) + tid;

    float q0[MPT], q1[MPT], q2[MPT], mn[MPT];
    #pragma unroll
    for (int j = 0; j < MPT; ++j) {
        const float* q = c2 + ((size_t)b * L2 + mbase + j * BLK) * 3;
        q0[j] = q[0] - EPS; q1[j] = q[1] - EPS; q2[j] = q[2] - EPS;
        mn[j] = FLT_BIG;
    }

    // 2 l's per iteration; one broadcast ds_read_b128 feeds 8 m's.
    #pragma unroll 2
    for (int l = 0; l < CLK; l += 2) {
        float4 pa = tile[l], pb = tile[l + 1];
        #pragma unroll
        for (int j = 0; j < MPT; ++j) {
            float ta = fmaf(pa.w, q2[j], fmaf(pa.z, q1[j], fmaf(pa.y, q0[j], pa.x)));
            float tb = fmaf(pb.w, q2[j], fmaf(pb.z, q1[j], fmaf(pb.y, q0[j], pb.x)));
            mn[j] = fminf(mn[j], fminf(ta, tb));
        }
    }

    float* dst = part + ((size_t)b * NCHUNK + chunk) * L2;
    #pragma unroll
    for (int j = 0; j < MPT; ++j) {
        const float qq = fmaf(q0[j], q0[j], fmaf(q1[j], q1[j], q2[j] * q2[j]));
        dst[mbase + j * BLK] = mn[j] + qq;
    }
}

// Dispatch 2. Grid (L2/BLK, B) = 64 blocks, 256 threads; thread owns one m:
// min over 32 chunks, sqrt, fixed-order block reduce, one atomicAdd per block.
__global__ void __launch_bounds__(BLK)
k_tail(const float* __restrict__ part, const float* __restrict__ res,
       float* __restrict__ out, int L2) {
    const int b = blockIdx.y;
    const int m = blockIdx.x * BLK + threadIdx.x;

    float v = FLT_BIG;
    #pragma unroll 8
    for (int c = 0; c < NCHUNK; ++c)
        v = fminf(v, part[((size_t)b * NCHUNK + c) * L2 + m]);
    float sum = sqrtf(fmaxf(v, 0.0f));

    // Wave shuffle reduce (fixed order), then LDS across 4 waves.
    #pragma unroll
    for (int s = 32; s > 0; s >>= 1)
        sum += __shfl_down(sum, s, 64);

    __shared__ float wred[BLK / 64];
    const int wid = threadIdx.x >> 6;
    if ((threadIdx.x & 63) == 0) wred[wid] = sum;
    __syncthreads();

    if (threadIdx.x == 0) {
        float tot = 0.0f;
        #pragma unroll
        for (int w = 0; w < BLK / 64; ++w) tot += wred[w];
        atomicAdd(&out[b], tot * res[0] / (float)L2);
    }
}

extern "C" void kernel_launch(void* const* d_in, const int* in_sizes, int n_in,
                              void* d_out, int out_size, void* d_ws, size_t ws_size,
                              hipStream_t stream) {
    const float* c1  = (const float*)d_in[0];
    const float* c2  = (const float*)d_in[1];
    const float* res = (const float*)d_in[2];
    float* out = (float*)d_out;

    const int B = out_size;                 // 4
    const int D = 3;
    const int L1 = in_sizes[0] / (B * D);   // 4096
    const int L2 = in_sizes[1] / (B * D);   // 4096

    float* part = (float*)d_ws;             // B*NCHUNK*L2 floats (2 MiB)

    dim3 g1(NMB, NCHUNK, B);                // 256 blocks
    k_min<<<g1, BLK, 0, stream>>>(c1, c2, part, out, L1, L2);

    dim3 g2(L2 / BLK, B);                   // 64 blocks
    k_tail<<<g2, BLK, 0, stream>>>(part, res, out, L2);
}

// Round 11
// 18.551 us; speedup vs baseline: 4.0086x; 1.0404x over previous
//
#include <hip/hip_runtime.h>
#include <math.h>

#define EPS 1e-6f
#define FLT_BIG 3.402823466e+38f

constexpr int BLK = 256;     // threads per block
constexpr int MPT = 8;       // m's per thread (amortize LDS broadcast over 8 m's)
constexpr int NCHUNK = 64;   // l-chunks (grid.y) -> 512 blocks = 2 waves/SIMD
constexpr int NMB = 2;       // m-blocks (grid.x): NMB*BLK*MPT = 4096 = L2
constexpr int CLK = 64;      // l's per chunk (L1 / NCHUNK)

// Dispatch 1. Grid (NMB, NCHUNK, B) = 512 blocks, 256 threads.
// Per (b,chunk): stage CLK points of c1 as (||p||^2,-2x,-2y,-2z) in LDS; each
// thread computes chunk-partial min_l(||p||^2 - 2 p.q) + ||q||^2 for 8 m's
// (q = c2[m] - eps) and stores to part[b][chunk][m]. Plain stores, no atomics.
// Block (0,0,b) thread 0 also zeroes out[b] (stream-ordered before k_tail).
__global__ void __launch_bounds__(BLK)
k_min(const float* __restrict__ c1, const float* __restrict__ c2,
      float* __restrict__ part, float* __restrict__ out, int L1, int L2) {
    __shared__ float4 tile[CLK];

    const int mb = blockIdx.x, chunk = blockIdx.y, b = blockIdx.z;
    const int tid = threadIdx.x;

    if (mb == 0 && chunk == 0 && tid == 0) out[b] = 0.0f;

    const int l0 = chunk * CLK;
    const float* src = c1 + ((size_t)b * L1 + l0) * 3;
    if (tid < CLK) {
        float x = src[3 * tid], y = src[3 * tid + 1], z = src[3 * tid + 2];
        tile[tid] = make_float4(fmaf(x, x, fmaf(y, y, z * z)),
                                -2.0f * x, -2.0f * y, -2.0f * z);
    }
    __syncthreads();

    const int mbase = mb * (BLK * MPT) + tid;

    float q0[MPT], q1[MPT], q2[MPT], mn[MPT];
    #pragma unroll
    for (int j = 0; j < MPT; ++j) {
        const float* q = c2 + ((size_t)b * L2 + mbase + j * BLK) * 3;
        q0[j] = q[0] - EPS; q1[j] = q[1] - EPS; q2[j] = q[2] - EPS;
        mn[j] = FLT_BIG;
    }

    // 2 l's per iteration; one broadcast ds_read_b128 feeds 8 m's.
    #pragma unroll 2
    for (int l = 0; l < CLK; l += 2) {
        float4 pa = tile[l], pb = tile[l + 1];
        #pragma unroll
        for (int j = 0; j < MPT; ++j) {
            float ta = fmaf(pa.w, q2[j], fmaf(pa.z, q1[j], fmaf(pa.y, q0[j], pa.x)));
            float tb = fmaf(pb.w, q2[j], fmaf(pb.z, q1[j], fmaf(pb.y, q0[j], pb.x)));
            mn[j] = fminf(mn[j], fminf(ta, tb));
        }
    }

    float* dst = part + ((size_t)b * NCHUNK + chunk) * L2;
    #pragma unroll
    for (int j = 0; j < MPT; ++j) {
        const float qq = fmaf(q0[j], q0[j], fmaf(q1[j], q1[j], q2[j] * q2[j]));
        dst[mbase + j * BLK] = mn[j] + qq;
    }
}

// Dispatch 2. Grid (L2/BLK, B) = 64 blocks, 256 threads; thread owns one m:
// min over 64 chunks, sqrt, fixed-order block reduce, one atomicAdd per block.
__global__ void __launch_bounds__(BLK)
k_tail(const float* __restrict__ part, const float* __restrict__ res,
       float* __restrict__ out, int L2) {
    const int b = blockIdx.y;
    const int m = blockIdx.x * BLK + threadIdx.x;

    float v = FLT_BIG;
    #pragma unroll 8
    for (int c = 0; c < NCHUNK; ++c)
        v = fminf(v, part[((size_t)b * NCHUNK + c) * L2 + m]);
    float sum = sqrtf(fmaxf(v, 0.0f));

    // Wave shuffle reduce (fixed order), then LDS across 4 waves.
    #pragma unroll
    for (int s = 32; s > 0; s >>= 1)
        sum += __shfl_down(sum, s, 64);

    __shared__ float wred[BLK / 64];
    const int wid = threadIdx.x >> 6;
    if ((threadIdx.x & 63) == 0) wred[wid] = sum;
    __syncthreads();

    if (threadIdx.x == 0) {
        float tot = 0.0f;
        #pragma unroll
        for (int w = 0; w < BLK / 64; ++w) tot += wred[w];
        atomicAdd(&out[b], tot * res[0] / (float)L2);
    }
}

extern "C" void kernel_launch(void* const* d_in, const int* in_sizes, int n_in,
                              void* d_out, int out_size, void* d_ws, size_t ws_size,
                              hipStream_t stream) {
    const float* c1  = (const float*)d_in[0];
    const float* c2  = (const float*)d_in[1];
    const float* res = (const float*)d_in[2];
    float* out = (float*)d_out;

    const int B = out_size;                 // 4
    const int D = 3;
    const int L1 = in_sizes[0] / (B * D);   // 4096
    const int L2 = in_sizes[1] / (B * D);   // 4096

    float* part = (float*)d_ws;             // B*NCHUNK*L2 floats (4 MiB)

    dim3 g1(NMB, NCHUNK, B);                // 512 blocks
    k_min<<<g1, BLK, 0, stream>>>(c1, c2, part, out, L1, L2);

    dim3 g2(L2 / BLK, B);                   // 64 blocks
    k_tail<<<g2, BLK, 0, stream>>>(part, res, out, L2);
}